// Round 4
// baseline (420.130 us; speedup 1.0000x reference)
//
#include <hip/hip_runtime.h>
#include <hip/hip_bf16.h>

#define EPSF 1e-5f

typedef int v4i __attribute__((ext_vector_type(4)));
typedef int v16i __attribute__((ext_vector_type(16)));
typedef short v8s __attribute__((ext_vector_type(8)));

static constexpr int BB = 4, TT = 1024, DD = 2048, HH = 8192;
static constexpr int MROWS = BB * TT;                   // 4096
static constexpr long long WCOUNT = (long long)DD * HH; // 2^24 per weight

// ---------------------------------------------------------------- helpers

__device__ __forceinline__ void async_copy16(const void* g, void* l) {
  __builtin_amdgcn_global_load_lds(
      (const __attribute__((address_space(1))) unsigned int*)g,
      (__attribute__((address_space(3))) unsigned int*)l,
      16, 0, 0);
}

__device__ __forceinline__ int pack4(float a, float b, float c, float d,
                                     float scale, float lo, float hi) {
  int ia = (int)fminf(fmaxf(rintf(a * scale), lo), hi);
  int ib = (int)fminf(fmaxf(rintf(b * scale), lo), hi);
  int ic = (int)fminf(fmaxf(rintf(c * scale), lo), hi);
  int id = (int)fminf(fmaxf(rintf(d * scale), lo), hi);
  return (ia & 0xff) | ((ib & 0xff) << 8) | ((ic & 0xff) << 16) | ((id & 0xff) << 24);
}

__device__ __forceinline__ float abs4(float4 v) {
  return fmaxf(fmaxf(fabsf(v.x), fabsf(v.y)), fmaxf(fabsf(v.z), fabsf(v.w)));
}

__device__ __forceinline__ int blockMaxI256(int v) {
  #pragma unroll
  for (int off = 32; off; off >>= 1) v = max(v, __shfl_down(v, off, 64));
  __shared__ int sm[4];
  int lane = threadIdx.x & 63, wv = threadIdx.x >> 6;
  if (lane == 0) sm[wv] = v;
  __syncthreads();
  return max(max(sm[0], sm[1]), max(sm[2], sm[3]));
}

// XCD-aware tile swizzle: id%8 class (heuristic XCD) owns a contiguous patch.
__device__ __forceinline__ void swizzle_tiles(int& mt, int& nt) {
  int Mt = gridDim.y, Nt = gridDim.x;
  int id = blockIdx.y * Nt + blockIdx.x;
  int c = id & 7, k = id >> 3;
  int pm = (Mt >= Nt) ? 4 : 2;
  int PM = Mt / pm, PN = Nt / (8 / pm);
  int pr = c % pm, pc = c / pm;
  mt = pr * PM + (k % PM);
  nt = pc * PN + (k / PM);
}

// ---------------------------------------------------------------- prep: |w| partial sums + act-quant x (fused, independent work)

__global__ __launch_bounds__(256) void prep_kernel(
    const float* __restrict__ w1, const float* __restrict__ w2,
    const float* __restrict__ x, float* __restrict__ partials,
    signed char* __restrict__ xq, float* __restrict__ ascale) {
  __shared__ float sm[4];
  const int bid = blockIdx.x, t = threadIdx.x;
  const int lane = t & 63, wv = t >> 6;

  if (bid < 4096) {
    const int y = bid >> 11, b = bid & 2047;
    const float4* w4 = (const float4*)(y ? w2 : w1);
    const long long base = (long long)b * 2048;
    float4 u[8];
    #pragma unroll
    for (int k = 0; k < 8; k++) u[k] = w4[base + t + k * 256];
    float s = 0.f;
    #pragma unroll
    for (int k = 0; k < 8; k++)
      s += fabsf(u[k].x) + fabsf(u[k].y) + fabsf(u[k].z) + fabsf(u[k].w);
    #pragma unroll
    for (int off = 32; off; off >>= 1) s += __shfl_down(s, off, 64);
    if (lane == 0) sm[wv] = s;
    __syncthreads();
    if (t == 0) partials[y * 2048 + b] = sm[0] + sm[1] + sm[2] + sm[3];
  } else {
    int row = (bid - 4096) * 4 + wv;
    const float4* xr = (const float4*)(x + (size_t)row * DD);
    float4 v[8];
    #pragma unroll
    for (int j = 0; j < 8; j++) v[j] = xr[lane + j * 64];
    float m = 0.f;
    #pragma unroll
    for (int j = 0; j < 8; j++) m = fmaxf(m, abs4(v[j]));
    #pragma unroll
    for (int off = 32; off; off >>= 1) m = fmaxf(m, __shfl_down(m, off, 64));
    m = __shfl(m, 0, 64);
    float am = fmaxf(m, EPSF);
    float scale = 127.0f / am;
    int* out = (int*)(xq + (size_t)row * DD);
    #pragma unroll
    for (int j = 0; j < 8; j++)
      out[lane + j * 64] = pack4(v[j].x, v[j].y, v[j].z, v[j].w, scale, -128.f, 127.f);
    if (lane == 0) ascale[row] = am / 127.0f;
  }
}

// ---------------------------------------------------------------- ternary quant

__global__ __launch_bounds__(256) void quant_w_kernel(
    const float* __restrict__ w1, const float* __restrict__ w2,
    const float* __restrict__ partials, float* __restrict__ meanw,
    signed char* __restrict__ q1, signed char* __restrict__ q2) {
  const int y = blockIdx.y, bid = blockIdx.x, t = threadIdx.x;
  const int lane = t & 63, wv = t >> 6;

  double d = 0.0;
  #pragma unroll
  for (int j = 0; j < 8; j++) d += (double)partials[y * 2048 + t + j * 256];
  #pragma unroll
  for (int off = 32; off; off >>= 1) d += __shfl_down(d, off, 64);
  __shared__ double smd[4];
  if (lane == 0) smd[wv] = d;
  __syncthreads();
  double sum = smd[0] + smd[1] + smd[2] + smd[3];
  float mean = fmaxf((float)(sum * (1.0 / (double)WCOUNT)), EPSF);
  if (bid == 0 && t == 0) meanw[y] = mean;
  float sc = 1.0f / mean;

  const float4* w4 = (const float4*)(y ? w2 : w1);
  int* q4 = (int*)(y ? q2 : q1);
  const long long base = (long long)bid * 2048;
  float4 u[8];
  #pragma unroll
  for (int k = 0; k < 8; k++) u[k] = w4[base + t + k * 256];
  #pragma unroll
  for (int k = 0; k < 8; k++)
    q4[base + t + k * 256] = pack4(u[k].x, u[k].y, u[k].z, u[k].w, sc, -1.f, 1.f);
}

// ---------------------------------------------------------------- act quant h (int16 in, int2 packed stores)

__global__ __launch_bounds__(256) void quant_h_kernel(
    const short* __restrict__ h, signed char* __restrict__ hq,
    float* __restrict__ a2, const float* __restrict__ a1,
    const float* __restrict__ meanw) {
  int row = blockIdx.x;
  int t = threadIdx.x;
  const v8s* hr = (const v8s*)(h + (size_t)row * HH);
  v8s v[4];
  #pragma unroll
  for (int i = 0; i < 4; i++) v[i] = hr[t + i * 256];
  int mx = 0;
  #pragma unroll
  for (int i = 0; i < 4; i++)
    #pragma unroll
    for (int j = 0; j < 8; j++) mx = max(mx, (int)v[i][j]);
  int bmx = blockMaxI256(mx);
  float f = a1[row] * meanw[0];      // per-row dequant factor (exact ref path)
  float maxh = (float)bmx * f;       // == max_j fl(r_j*f): fl monotone, f>=0
  float am = fmaxf(maxh, EPSF);
  float scale = 127.0f / am;
  int2* out = (int2*)(hq + (size_t)row * HH);
  #pragma unroll
  for (int i = 0; i < 4; i++) {
    int p0 = pack4((float)v[i][0] * f, (float)v[i][1] * f, (float)v[i][2] * f,
                   (float)v[i][3] * f, scale, -128.f, 127.f);
    int p1 = pack4((float)v[i][4] * f, (float)v[i][5] * f, (float)v[i][6] * f,
                   (float)v[i][7] * f, scale, -128.f, 127.f);
    out[t + i * 256] = int2{p0, p1};
  }
  if (t == 0) a2[row] = am / 127.0f;
}

// ---------------------------------------------------------------- int8 GEMM: 128x128, BK=64, double-buffered, 4 blocks/CU
// C[M][N] = sum_k A[M][K]*B[N][K].  Same fragment geometry/swizzle/epilogue
// as R3 (32x32x32 frags, XOR 16B-chunk swizzle c^(r&(CH-1)), verified), but:
//  - BK=64 => As+Bs = 2 x 2 x 8KB = 32 KB LDS, __launch_bounds__(256,4):
//    4 blocks/CU (16 waves) vs R3's 2 => cross-block desync fills the
//    LDS-read-burst / MFMA-burst serialization measured at 2 blocks.
//  - classic double-buffer: stage(k+1) issued BEFORE compute(k), so the
//    __syncthreads() vmcnt(0) drain waits on loads that are a full compute
//    phase old (latency hidden by construction, not by luck).
// MODE 1: relu -> int16 store. MODE 0: scaled fp32 store.

template <int MODE>
__global__ __launch_bounds__(256, 4) void gemm_i8_kernel(
    const signed char* __restrict__ A, const signed char* __restrict__ B,
    void* __restrict__ Cout, const float* __restrict__ ascale,
    const float* __restrict__ wmean_p, int M, int N, int K) {
  constexpr int BK = 64;
  constexpr int CH = BK / 16;        // 4 chunks of 16B per row
  constexpr int SEGROWS = 1024 / BK; // 16 rows per 1KB segment
  constexpr int SPW = BK / 32;       // 2 staging instrs per wave per operand
  __shared__ signed char As[2][128 * BK];
  __shared__ signed char Bs[2][128 * BK];

  const int t = threadIdx.x;
  const int lane = t & 63, wv = t >> 6;
  const int wm = wv >> 1, wn = wv & 1;
  int mt, nt;
  swizzle_tiles(mt, nt);
  const int m0 = mt * 128, n0 = nt * 128;
  const int hf = lane >> 5;          // K-half for 32x32 frags

  const signed char* aSrc[SPW];
  const signed char* bSrc[SPW];
  #pragma unroll
  for (int i = 0; i < SPW; i++) {
    int seg = wv * SPW + i;
    int r = seg * SEGROWS + lane / CH;
    int c = (lane % CH) ^ (r & (CH - 1));
    aSrc[i] = A + (size_t)(m0 + r) * K + c * 16;
    bSrc[i] = B + (size_t)(n0 + r) * K + c * 16;
  }

  v16i acc[2][2];
  #pragma unroll
  for (int i = 0; i < 2; i++)
    #pragma unroll
    for (int j = 0; j < 2; j++) {
      v16i z = {0, 0, 0, 0, 0, 0, 0, 0, 0, 0, 0, 0, 0, 0, 0, 0};
      acc[i][j] = z;
    }

  int rowA[2], rowB[2];
  #pragma unroll
  for (int i = 0; i < 2; i++) {
    rowA[i] = wm * 64 + i * 32 + (lane & 31);
    rowB[i] = wn * 64 + i * 32 + (lane & 31);
  }

  auto stage = [&](int kt, int bu) {
    #pragma unroll
    for (int i = 0; i < SPW; i++) {
      async_copy16(aSrc[i] + (size_t)kt * BK, &As[bu][(wv * SPW + i) * 1024]);
      async_copy16(bSrc[i] + (size_t)kt * BK, &Bs[bu][(wv * SPW + i) * 1024]);
    }
  };

  const int NK = K / BK;
  stage(0, 0);
  __syncthreads();                       // drains vmcnt(0): tile 0 landed

  for (int kt = 0; kt < NK; ++kt) {
    if (kt + 1 < NK) stage(kt + 1, (kt + 1) & 1);
    const signed char* as_ = As[kt & 1];
    const signed char* bs_ = Bs[kt & 1];
    #pragma unroll
    for (int ks = 0; ks < BK / 32; ks++) {
      v4i af[2], bf[2];
      #pragma unroll
      for (int i = 0; i < 2; i++) {
        int ca = (ks * 2 + hf) ^ (rowA[i] & (CH - 1));
        af[i] = *(const v4i*)(as_ + rowA[i] * BK + ca * 16);
        int cb = (ks * 2 + hf) ^ (rowB[i] & (CH - 1));
        bf[i] = *(const v4i*)(bs_ + rowB[i] * BK + cb * 16);
      }
      #pragma unroll
      for (int i = 0; i < 2; i++)
        #pragma unroll
        for (int j = 0; j < 2; j++)
          acc[i][j] = __builtin_amdgcn_mfma_i32_32x32x32_i8(af[i], bf[j], acc[i][j], 0, 0, 0);
    }
    // waits vmcnt(0): stage(kt+1), issued one full compute phase ago;
    // lgkmcnt(0): this tile's ds_reads done -> buffer (kt+1)&1 safe to reuse
    __syncthreads();
  }

  if constexpr (MODE == 1) {
    short* C = (short*)Cout;
    #pragma unroll
    for (int i = 0; i < 2; i++) {
      #pragma unroll
      for (int e = 0; e < 16; e++) {
        int m = m0 + wm * 64 + i * 32 + (e & 3) + 8 * (e >> 2) + 4 * hf;
        #pragma unroll
        for (int j = 0; j < 2; j++) {
          int n = n0 + wn * 64 + j * 32 + (lane & 31);
          int r = acc[i][j][e];
          r = r < 0 ? 0 : (r > 32767 ? 32767 : r);
          C[(size_t)m * N + n] = (short)r;
        }
      }
    }
  } else {
    float* C = (float*)Cout;
    float wmean = wmean_p[0];
    #pragma unroll
    for (int i = 0; i < 2; i++) {
      #pragma unroll
      for (int e = 0; e < 16; e++) {
        int m = m0 + wm * 64 + i * 32 + (e & 3) + 8 * (e >> 2) + 4 * hf;
        float f = ascale[m] * wmean;
        #pragma unroll
        for (int j = 0; j < 2; j++) {
          int n = n0 + wn * 64 + j * 32 + (lane & 31);
          C[(size_t)m * N + n] = (float)acc[i][j][e] * f;
        }
      }
    }
  }
}

// ---------------------------------------------------------------- launch

extern "C" void kernel_launch(void* const* d_in, const int* in_sizes, int n_in,
                              void* d_out, int out_size, void* d_ws, size_t ws_size,
                              hipStream_t stream) {
  const float* x  = (const float*)d_in[0];
  const float* w1 = (const float*)d_in[1];
  const float* w2 = (const float*)d_in[2];
  float* out = (float*)d_out;

  char* ws = (char*)d_ws;
  float* meanw = (float*)ws;                                // 2 f32
  float* partials = (float*)(ws + 1024);                    // 4096 f32 (16 KB)
  float* a1 = (float*)(ws + 20480);                         // 4096 f32
  float* a2 = (float*)(ws + 40960);                         // 4096 f32
  signed char* w1q = (signed char*)(ws + 65536);            // 16 MB
  signed char* w2q = w1q + (size_t)WCOUNT;                  // 16 MB
  signed char* xq  = w2q + (size_t)WCOUNT;                  // 8 MB
  signed char* hq  = xq + (size_t)MROWS * DD;               // 32 MB
  short* h16 = (short*)(hq + (size_t)MROWS * HH);           // 64 MB int16

  // prep: weight |.| partials (4096 blocks) + x act-quant (1024 blocks)
  prep_kernel<<<5120, 256, 0, stream>>>(w1, w2, x, partials, xq, a1);
  quant_w_kernel<<<dim3(2048, 2), 256, 0, stream>>>(w1, w2, partials, meanw, w1q, w2q);
  // GEMM1: M=4096, N=8192, K=2048 — BK=64 dbuf, relu->int16
  gemm_i8_kernel<1><<<dim3(HH / 128, MROWS / 128), 256, 0, stream>>>(
      xq, w1q, h16, nullptr, meanw, MROWS, HH, DD);
  quant_h_kernel<<<MROWS, 256, 0, stream>>>(h16, hq, a2, a1, meanw);
  // GEMM2: M=4096, N=2048, K=8192 — BK=64 dbuf, scaled fp32
  gemm_i8_kernel<0><<<dim3(DD / 128, MROWS / 128), 256, 0, stream>>>(
      hq, w2q, out, a2, &meanw[1], MROWS, DD, HH);
}